// Round 9
// baseline (6518.856 us; speedup 1.0000x reference)
//
#include <hip/hip_runtime.h>
#include <cstdint>
#include <cstddef>

// ---------------------------------------------------------------------------
// DeepCNNLSTM_EncoderMOE on MI355X (gfx950)
// Round 9: LSTM v9 — 4-way split, LDS-resident weights, per-thread demand ~70
// VGPRs (below every observed allocator grant). 256 WGs x 256 thr; thread owns
// one gate column: 48 VGPR pairs + 80 LDS pairs. readlane h-broadcast;
// R7/R8-verified flag sync extended to 4-way; XCD-co-located WG mapping.
// ---------------------------------------------------------------------------

#define DEVI __device__ __forceinline__

typedef _Float16 f16;
typedef _Float16 f16x8 __attribute__((ext_vector_type(8)));
typedef _Float16 f16x2 __attribute__((ext_vector_type(2)));
typedef float    f32x4 __attribute__((ext_vector_type(4)));
typedef unsigned int u32;
typedef unsigned short u16;

static constexpr int B   = 64;
static constexpr int T   = 512;
static constexpr int NC  = 10;
static constexpr int NU  = 192;   // slot-units: s=0,1 experts; s=2 shared

// ---- workspace layout (bytes) ----
constexpr size_t SZ_WS1 = (size_t)5*64*32*2;
constexpr size_t SZ_WS2 = (size_t)5*128*64*2;
constexpr size_t SZ_WS3 = (size_t)5*256*128*2;
constexpr size_t SZ_WE1 = 8*SZ_WS1;
constexpr size_t SZ_WE2 = 8*SZ_WS2;
constexpr size_t SZ_WE3 = 8*SZ_WS3;
constexpr size_t SZ_WR  = (size_t)5*128*32*2;
constexpr size_t SZ_WIH = (size_t)1024*256*2;
constexpr size_t SZ_WHH = (size_t)128*1024*4;
constexpr size_t SZ_ACT0 = (size_t)B*T*32*2;
constexpr size_t SZ_RACT = (size_t)B*T*128*2;
constexpr size_t SZ_AMIX = (size_t)B*T*256*2;
constexpr size_t SZ_CONV = (size_t)NU*T*256*2;
constexpr size_t SZ_A1   = (size_t)NU*T*64*2;
constexpr size_t SZ_A2   = (size_t)NU*T*128*2;
constexpr size_t SZ_U    = (size_t)B*T*1024*2;     // aliases CONV+A1+A2
constexpr size_t SZ_STAT = (size_t)NU*8*2*4;
constexpr size_t SZ_STATR= (size_t)B*8*2*4;
constexpr size_t SZ_RH   = (size_t)B*128*4;
constexpr size_t SZ_EIDX = (size_t)B*2*4;
constexpr size_t SZ_SWT  = (size_t)B*2*4;
constexpr size_t SZ_HT   = (size_t)B*256*4;
constexpr size_t SZ_HX   = (size_t)B*2*128*4;      // [b][par][128] u32
constexpr size_t SZ_FLG  = (size_t)256*4;

constexpr size_t OFF_WS1  = 0;
constexpr size_t OFF_WS2  = OFF_WS1 + SZ_WS1;
constexpr size_t OFF_WS3  = OFF_WS2 + SZ_WS2;
constexpr size_t OFF_WE1  = OFF_WS3 + SZ_WS3;
constexpr size_t OFF_WE2  = OFF_WE1 + SZ_WE1;
constexpr size_t OFF_WE3  = OFF_WE2 + SZ_WE2;
constexpr size_t OFF_WR   = OFF_WE3 + SZ_WE3;
constexpr size_t OFF_WIH  = OFF_WR  + SZ_WR;
constexpr size_t OFF_WHH  = OFF_WIH + SZ_WIH;
constexpr size_t OFF_ACT0 = OFF_WHH + SZ_WHH;
constexpr size_t OFF_RACT = OFF_ACT0 + SZ_ACT0;
constexpr size_t OFF_AMIX = OFF_RACT + SZ_RACT;
constexpr size_t OFF_CONV = OFF_AMIX + SZ_AMIX;
constexpr size_t OFF_A1   = OFF_CONV + SZ_CONV;
constexpr size_t OFF_A2   = OFF_A1 + SZ_A1;
constexpr size_t OFF_U    = OFF_CONV;              // alias
constexpr size_t OFF_STAT = OFF_A2 + SZ_A2;
constexpr size_t OFF_STATR= OFF_STAT + SZ_STAT;
constexpr size_t OFF_RH   = OFF_STATR + SZ_STATR;
constexpr size_t OFF_EIDX = OFF_RH + SZ_RH;
constexpr size_t OFF_SWT  = OFF_EIDX + SZ_EIDX;
constexpr size_t OFF_HT   = OFF_SWT + SZ_SWT;
constexpr size_t OFF_HX   = OFF_HT + SZ_HT;
constexpr size_t OFF_FLG  = OFF_HX + SZ_HX;
constexpr size_t WS_TOTAL = OFF_FLG + SZ_FLG;

static_assert(SZ_U <= SZ_CONV + SZ_A1 + SZ_A2, "U alias overflow");

DEVI float geluf(float x){ return 0.5f*x*(1.f + erff(x*0.70710678118654752f)); }
DEVI float fsig(float x){ return 1.f/(1.f + __expf(-x)); }
DEVI float ftanh(float x){ float e = __expf(-2.f*x); return (1.f-e)/(1.f+e); }

// ---------------------------------------------------------------------------
// Weight prep
// ---------------------------------------------------------------------------
DEVI void fill_convw(f16* dst, const float* src, int COUT, int CI, int CIP, int idx){
  int s  = idx / (COUT*CIP);
  int r  = idx - s*(COUT*CIP);
  int co = r / CIP;
  int ci = r - co*CIP;
  float v = (ci < CI) ? src[((size_t)co*CI + ci)*5 + s] : 0.f;
  dst[idx] = (f16)v;
}

__global__ __launch_bounds__(256) void k_prep_w(
    const float* eW1, const float* eW2, const float* eW3,
    const float* sW1, const float* sW2, const float* sW3, const float* rW,
    const float* Wih, const float* Whh, char* ws)
{
  int i = blockIdx.x*256 + threadIdx.x;
  if (i < 10240){ fill_convw((f16*)(ws+OFF_WS1), sW1, 64, 16, 32, i); return; } i -= 10240;
  if (i < 40960){ fill_convw((f16*)(ws+OFF_WS2), sW2, 128, 64, 64, i); return; } i -= 40960;
  if (i < 163840){ fill_convw((f16*)(ws+OFF_WS3), sW3, 256, 128, 128, i); return; } i -= 163840;
  if (i < 81920){ int e=i/10240, r=i-e*10240;
    fill_convw((f16*)(ws+OFF_WE1)+ (size_t)e*10240, eW1 + (size_t)e*64*16*5, 64, 16, 32, r); return; } i -= 81920;
  if (i < 327680){ int e=i/40960, r=i-e*40960;
    fill_convw((f16*)(ws+OFF_WE2)+ (size_t)e*40960, eW2 + (size_t)e*128*64*5, 128, 64, 64, r); return; } i -= 327680;
  if (i < 1310720){ int e=i/163840, r=i-e*163840;
    fill_convw((f16*)(ws+OFF_WE3)+ (size_t)e*163840, eW3 + (size_t)e*163840, 256, 128, 128, r); return; } i -= 1310720;
  if (i < 20480){ fill_convw((f16*)(ws+OFF_WR), rW, 128, 16, 32, i); return; } i -= 20480;
  if (i < 262144){ // W_ih (256,1024) -> [j][k]
    int j = i >> 8, k = i & 255;
    ((f16*)(ws+OFF_WIH))[i] = (f16)Wih[(size_t)k*1024 + j]; return; } i -= 262144;
  if (i < 131072){ // W_hh -> packed row-pairs [pair][1024]
    int i2 = i >> 10, j = i & 1023;
    f16 a = (f16)Whh[(size_t)(2*i2)*1024 + j];
    f16 b = (f16)Whh[(size_t)(2*i2+1)*1024 + j];
    u32 u = (u32)__builtin_bit_cast(unsigned short, a)
          | ((u32)__builtin_bit_cast(unsigned short, b) << 16);
    ((u32*)(ws+OFF_WHH))[i] = u; return; }
}

__global__ __launch_bounds__(256) void k_prep_x(const float* __restrict__ x, char* ws){
  int idx = blockIdx.x*256 + threadIdx.x;
  if (idx >= B*T*32) return;
  int b = idx/(T*32); int r = idx - b*(T*32); int t = r >> 5; int c = r & 31;
  f16 v = (c < 16) ? (f16)x[((size_t)b*16 + c)*T + t] : (f16)0.f;
  ((f16*)(ws+OFF_ACT0))[idx] = v;
}

// ---------------------------------------------------------------------------
// Conv / GEMM via MFMA f16, slot-unit grid (blockIdx.z = unit).
// ---------------------------------------------------------------------------
template<int CIN, int NSHIFT>
__global__ __launch_bounds__(256) void k_conv(
    const f16* __restrict__ act, long actUnitStride,
    const f16* __restrict__ wtS, const f16* __restrict__ wtE, long wtEStride,
    const int* __restrict__ eidx,
    f16* __restrict__ outp, const float* __restrict__ bias, int COUT)
{
  int u = blockIdx.z;
  int s = u >> 6, b = u & 63;
  const f16* wt = wtS;
  if (eidx && s < 2) wt = wtE + (size_t)eidx[b*2+s]*wtEStride;
  const f16* abase = act + (actUnitStride ? (size_t)u*actUnitStride
                                          : (size_t)b*T*CIN);
  f16* obase = outp + (size_t)u*T*COUT;

  int t0 = blockIdx.x << 6;
  int n0 = blockIdx.y << 6;
  int tid  = threadIdx.x;
  int wave = tid >> 6, lane = tid & 63;
  int lr = lane & 15, lk = lane >> 4;

  f32x4 acc[4];
  #pragma unroll
  for (int nf=0; nf<4; ++nf) acc[nf] = f32x4{0.f,0.f,0.f,0.f};

  int trow = t0 + wave*16 + lr;

  #pragma unroll
  for (int sh=0; sh<NSHIFT; ++sh){
    int tg = (NSHIFT==5) ? (trow + sh - 2) : trow;
    bool valid = (unsigned)tg < (unsigned)T;
    const f16* arow = abase + (long)tg*CIN + lk*8;
    #pragma unroll
    for (int c0=0; c0<CIN; c0+=32){
      f16x8 af = {(f16)0,(f16)0,(f16)0,(f16)0,(f16)0,(f16)0,(f16)0,(f16)0};
      if (valid) af = *(const f16x8*)(arow + c0);
      #pragma unroll
      for (int nf=0; nf<4; ++nf){
        int col = n0 + nf*16 + lr;
        f16x8 bf = *(const f16x8*)(wt + ((size_t)sh*COUT + col)*CIN + c0 + lk*8);
        acc[nf] = __builtin_amdgcn_mfma_f32_16x16x32_f16(af, bf, acc[nf], 0, 0, 0);
      }
    }
  }

  #pragma unroll
  for (int nf=0; nf<4; ++nf){
    int col = n0 + nf*16 + lr;
    float bv = bias ? bias[col] : 0.f;
    #pragma unroll
    for (int r=0; r<4; ++r){
      int trw = t0 + wave*16 + lk*4 + r;
      obase[(size_t)trw*COUT + col] = (f16)(acc[nf][r] + bv);
    }
  }
}

// ---------------------------------------------------------------------------
// GroupNorm stats per (unit, g)
// ---------------------------------------------------------------------------
template<int CPG>
__global__ __launch_bounds__(256) void k_gnstats(
    const f16* __restrict__ xin, float* __restrict__ stats)
{
  constexpr int C = CPG*8;
  constexpr int V = CPG/8;
  int u = blockIdx.x >> 3, g = blockIdx.x & 7;
  const f16* base = xin + (size_t)u*T*C + g*CPG;
  float sum = 0.f, ss = 0.f;
  for (int i = threadIdx.x; i < T*V; i += 256){
    int t = i / V, v = i - (i/V)*V;
    f16x8 xv = *(const f16x8*)(base + (size_t)t*C + v*8);
    #pragma unroll
    for (int k=0;k<8;++k){ float f = (float)xv[k]; sum += f; ss += f*f; }
  }
  #pragma unroll
  for (int off=32; off; off>>=1){ sum += __shfl_down(sum, off); ss += __shfl_down(ss, off); }
  __shared__ float rs[8];
  int wave = threadIdx.x >> 6, lane = threadIdx.x & 63;
  if (lane == 0){ rs[wave] = sum; rs[4+wave] = ss; }
  __syncthreads();
  if (threadIdx.x == 0){
    float S = rs[0]+rs[1]+rs[2]+rs[3], Q = rs[4]+rs[5]+rs[6]+rs[7];
    constexpr float N = (float)(CPG*T);
    float m = S/N;
    float var = Q/N - m*m;
    stats[(u*8+g)*2]   = m;
    stats[(u*8+g)*2+1] = rsqrtf(var + 1e-5f);
  }
}

// ---------------------------------------------------------------------------
// GN apply + GELU -> f16 act (slot region)
// ---------------------------------------------------------------------------
template<int CPG>
__global__ __launch_bounds__(256) void k_gnapply(
    const f16* __restrict__ xin, const float* __restrict__ stats,
    const float* __restrict__ gS, const float* __restrict__ bS,
    const float* __restrict__ gE, const float* __restrict__ bE,
    const int* __restrict__ eidx, f16* __restrict__ outp, int total8)
{
  constexpr int C = CPG*8;
  int idx = blockIdx.x*256 + threadIdx.x;
  if (idx >= total8) return;
  size_t base = (size_t)idx*8;
  int u = (int)(base / ((size_t)T*C));
  int s = u >> 6, b = u & 63;
  const float* gamma = gS; const float* beta = bS;
  if (eidx && s < 2){ int e = eidx[b*2+s]; gamma = gE + e*C; beta = bE + e*C; }
  int c0 = (int)(base % C);
  int g  = c0 / CPG;
  float m  = stats[(u*8+g)*2];
  float rstd = stats[(u*8+g)*2+1];
  f16x8 xv = *(const f16x8*)(xin + base);
  f16x8 h8;
  #pragma unroll
  for (int k=0; k<8; ++k){
    float xn = ((float)xv[k]-m)*rstd*gamma[c0+k] + beta[c0+k];
    h8[k] = (f16)geluf(xn);
  }
  *(f16x8*)(outp + base) = h8;
}

// ---------------------------------------------------------------------------
// L3 GN + GELU + weighted slot-mix -> amix f16
// ---------------------------------------------------------------------------
__global__ __launch_bounds__(256) void k_gnmix(
    const f16* __restrict__ conv, const float* __restrict__ stats,
    const float* __restrict__ sg, const float* __restrict__ sb,
    const float* __restrict__ eg, const float* __restrict__ eb,
    const int* __restrict__ eidx, const float* __restrict__ swt,
    f16* __restrict__ amix)
{
  size_t base = ((size_t)blockIdx.x*256 + threadIdx.x)*8;
  if (base >= (size_t)B*T*256) return;
  int b = (int)(base / ((size_t)T*256));
  size_t rem = base - (size_t)b*T*256;
  int c0 = (int)(rem & 255);
  int g  = c0 >> 5;
  float o[8] = {0.f,0.f,0.f,0.f,0.f,0.f,0.f,0.f};
  #pragma unroll
  for (int s=0; s<3; ++s){
    int u = s*64 + b;
    float w; const float *gamma, *beta;
    if (s < 2){ int e = eidx[b*2+s]; w = swt[b*2+s]; gamma = eg + e*256; beta = eb + e*256; }
    else      { w = 1.f; gamma = sg; beta = sb; }
    float m = stats[(u*8+g)*2], rstd = stats[(u*8+g)*2+1];
    f16x8 xv = *(const f16x8*)(conv + (size_t)u*T*256 + rem);
    #pragma unroll
    for (int k=0; k<8; ++k){
      float xn = ((float)xv[k]-m)*rstd*gamma[c0+k] + beta[c0+k];
      o[k] += w*geluf(xn);
    }
  }
  f16x8 h8;
  #pragma unroll
  for (int k=0; k<8; ++k) h8[k] = (f16)o[k];
  *(f16x8*)(amix + base) = h8;
}

// ---------------------------------------------------------------------------
// Router
// ---------------------------------------------------------------------------
__global__ __launch_bounds__(512) void k_gap(const f16* __restrict__ ract,
                                             float* __restrict__ rh){
  int b = blockIdx.x;
  int c = threadIdx.x & 127, st = threadIdx.x >> 7;
  const f16* p = ract + (size_t)b*T*128 + c;
  float s = 0.f;
  for (int t = st; t < T; t += 4) s += (float)p[(size_t)t*128];
  __shared__ float acc[512];
  acc[threadIdx.x] = s;
  __syncthreads();
  if (st == 0) rh[b*128 + c] = (acc[c] + acc[128+c] + acc[256+c] + acc[384+c]) * (1.f/(float)T);
}

__global__ __launch_bounds__(128) void k_router(
    const float* __restrict__ rh,
    const float* __restrict__ m1W, const float* __restrict__ m1b,
    const float* __restrict__ lng, const float* __restrict__ lnb,
    const float* __restrict__ m2W, const float* __restrict__ m2b,
    const float* __restrict__ gW,  const float* __restrict__ gb,
    int* __restrict__ eidx, float* __restrict__ swt)
{
  int b = blockIdx.x, j = threadIdx.x;
  __shared__ float sbuf[128];
  __shared__ float red[4];
  __shared__ float z2[64];
  sbuf[j] = rh[b*128 + j];
  __syncthreads();
  float acc = m1b[j];
  for (int k=0; k<128; ++k) acc += sbuf[k]*m1W[k*128 + j];
  float s1 = acc, s2 = acc*acc;
  #pragma unroll
  for (int off=32; off; off>>=1){ s1 += __shfl_down(s1, off); s2 += __shfl_down(s2, off); }
  int wid = j >> 6, lane = j & 63;
  if (lane == 0){ red[wid] = s1; red[2+wid] = s2; }
  __syncthreads();
  float S = red[0]+red[1], Q = red[2]+red[3];
  float m = S*(1.f/128.f), var = Q*(1.f/128.f) - m*m;
  float xn = (acc - m)*rsqrtf(var + 1e-5f)*lng[j] + lnb[j];
  float ge = geluf(xn);
  __syncthreads();
  sbuf[j] = ge;
  __syncthreads();
  if (j < 64){
    float a = m2b[j];
    for (int k=0; k<128; ++k) a += sbuf[k]*m2W[k*64 + j];
    z2[j] = a;
  }
  __syncthreads();
  if (j == 0){
    float lg[8];
    for (int e=0; e<8; ++e){
      float a = gb[e];
      for (int k=0; k<64; ++k) a += z2[k]*gW[k*8 + e];
      lg[e] = a;
    }
    float mx = lg[0];
    for (int e=1; e<8; ++e) mx = fmaxf(mx, lg[e]);
    float p[8], sum = 0.f;
    for (int e=0; e<8; ++e){ p[e] = __expf(lg[e]-mx); sum += p[e]; }
    float inv = 1.f/sum;
    for (int e=0; e<8; ++e) p[e] *= inv;
    int i1 = 0;
    for (int e=1; e<8; ++e) if (p[e] > p[i1]) i1 = e;
    int i2 = -1;
    for (int e=0; e<8; ++e){ if (e==i1) continue; if (i2 < 0 || p[e] > p[i2]) i2 = e; }
    float s = p[i1] + p[i2] + 1e-9f;
    eidx[b*2]   = i1;  swt[b*2]   = p[i1]/s;
    eidx[b*2+1] = i2;  swt[b*2+1] = p[i2]/s;
  }
}

// ---------------------------------------------------------------------------
// LSTM v9: 4-way split. 256 WGs, XCD-co-located mapping:
// w = (b&7) + 8*((b>>3)*4 + q) -> all 4 quarters of b share w%8 (same XCD).
// WG (b,q) owns dims [64q,64q+64) = 256 cols; thread j owns col
// (j>>6)*256 + q*64 + (j&63). Weights: pairs [0,48) in VGPR (48 regs),
// [48,128) in LDS uint4 wl4[20][256] (80 KB -> 1 WG/CU). h via readlane.
// 4-way h-exchange through hxs[b][par][128] + per-(b,q) flags (agent scope).
// ---------------------------------------------------------------------------
constexpr int PV9 = 48;
constexpr int KQ9 = 20;

DEVI float dot2acc(u32 wu, u32 hu, float acc){
#if __has_builtin(__builtin_amdgcn_fdot2)
  return __builtin_amdgcn_fdot2(__builtin_bit_cast(f16x2, wu),
                                __builtin_bit_cast(f16x2, hu), acc, false);
#else
  f16x2 a = __builtin_bit_cast(f16x2, wu), b = __builtin_bit_cast(f16x2, hu);
  return acc + (float)a.x*(float)b.x + (float)a.y*(float)b.y;
#endif
}

DEVI u32 rdlane(u32 v, int l){
#if __has_builtin(__builtin_amdgcn_readlane)
  return __builtin_amdgcn_readlane(v, l);
#else
  return (u32)__shfl((int)v, l);
#endif
}

__global__ __launch_bounds__(64) void k_reset(u32* flags){
  flags[threadIdx.x + blockIdx.x*64] = 0u;
}

__global__ __attribute__((amdgpu_flat_work_group_size(256,256), amdgpu_waves_per_eu(1,1)))
void k_lstm(const u32* __restrict__ whh, const f16* __restrict__ U,
            u32* __restrict__ hxs, u32* __restrict__ flags,
            float* __restrict__ hTout)
{
  int w = blockIdx.x;
  int bl = w & 7, k = w >> 3;
  int q = k & 3, bh = k >> 2;
  int b = bl | (bh << 3);
  int j = threadIdx.x;
  int gate = j >> 6, dloc = j & 63;
  int lane = j & 63;
  int col = gate*256 + q*64 + dloc;

  __shared__ uint4 wl4[KQ9*256];   // pairs [48,128): 80 KB
  __shared__ u32 hq[32];           // own packed h quarter (64 dims)
  __shared__ float gbuf[256];

  u32 wV[PV9];
  #pragma unroll
  for (int i=0; i<PV9; ++i) wV[i] = whh[(size_t)i*1024 + col];
  #pragma unroll
  for (int kk=0; kk<KQ9; ++kk)
    wl4[kk*256 + j] = uint4{ whh[(size_t)(PV9+4*kk+0)*1024 + col],
                             whh[(size_t)(PV9+4*kk+1)*1024 + col],
                             whh[(size_t)(PV9+4*kk+2)*1024 + col],
                             whh[(size_t)(PV9+4*kk+3)*1024 + col] };

  float cst = 0.f, hst = 0.f;
  const f16* Ub = U + (size_t)b*T*1024 + col;
  float unext = (float)Ub[0];
  u32 vLow = 0u, vHigh = 0u;       // packed h: dims 0..127 / 128..255
  int fbase = b << 2;
  int q1 = fbase + ((q+1)&3), q2 = fbase + ((q+2)&3), q3 = fbase + ((q+3)&3);
  __syncthreads();

  for (int t=0; t<T; ++t){
    float a0 = unext, a1 = 0.f;
    if (t+1 < T) unext = (float)Ub[(size_t)(t+1)*1024];
    // VGPR pairs 0..47 (h pairs 0..47 from vLow), 2 chains
    #pragma unroll
    for (int p=0; p<PV9; p+=2){
      a0 = dot2acc(wV[p],   rdlane(vLow, p),   a0);
      a1 = dot2acc(wV[p+1], rdlane(vLow, p+1), a1);
    }
    // LDS pairs 48..127 in uint4 quads
    #pragma unroll
    for (int kk=0; kk<KQ9; ++kk){
      uint4 qw = wl4[kk*256 + j];
      const int lp = PV9 + 4*kk;
      u32 s0 = (lp+0 < 64) ? rdlane(vLow, lp+0) : rdlane(vHigh, lp+0-64);
      u32 s1 = (lp+1 < 64) ? rdlane(vLow, lp+1) : rdlane(vHigh, lp+1-64);
      u32 s2 = (lp+2 < 64) ? rdlane(vLow, lp+2) : rdlane(vHigh, lp+2-64);
      u32 s3 = (lp+3 < 64) ? rdlane(vLow, lp+3) : rdlane(vHigh, lp+3-64);
      a0 = dot2acc(qw.x, s0, a0);
      a1 = dot2acc(qw.y, s1, a1);
      a0 = dot2acc(qw.z, s2, a0);
      a1 = dot2acc(qw.w, s3, a1);
    }
    gbuf[j] = a0 + a1;
    __syncthreads();                               // B1: gates ready
    if (j < 64){
      float gi = gbuf[j], gf = gbuf[64+j], gg = gbuf[128+j], go = gbuf[192+j];
      cst = fsig(gf)*cst + fsig(gi)*ftanh(gg);
      hst = fsig(go)*ftanh(cst);
      ((u16*)hq)[j] = __builtin_bit_cast(u16, (f16)hst);
    }
    __syncthreads();                               // B2: hq ready
    if (t+1 < T){
      int par = t & 1;
      size_t hb = ((size_t)b*2 + par)*128;
      if (j < 32)
        __hip_atomic_store(&hxs[hb + q*32 + j], hq[j], __ATOMIC_RELAXED,
                           __HIP_MEMORY_SCOPE_AGENT);
      __syncthreads();                             // B3: stores drained
      if (j == 0){
        __hip_atomic_store(&flags[fbase+q], (u32)(t+1), __ATOMIC_RELEASE,
                           __HIP_MEMORY_SCOPE_AGENT);
        for (;;){
          u32 f0 = __hip_atomic_load(&flags[q1], __ATOMIC_ACQUIRE, __HIP_MEMORY_SCOPE_AGENT);
          u32 f1 = __hip_atomic_load(&flags[q2], __ATOMIC_ACQUIRE, __HIP_MEMORY_SCOPE_AGENT);
          u32 f2 = __hip_atomic_load(&flags[q3], __ATOMIC_ACQUIRE, __HIP_MEMORY_SCOPE_AGENT);
          if (f0 >= (u32)(t+1) && f1 >= (u32)(t+1) && f2 >= (u32)(t+1)) break;
          __builtin_amdgcn_s_sleep(1);
        }
      }
      __syncthreads();                             // B4: all quarters visible
      vLow  = __hip_atomic_load(&hxs[hb + lane],      __ATOMIC_RELAXED, __HIP_MEMORY_SCOPE_AGENT);
      vHigh = __hip_atomic_load(&hxs[hb + 64 + lane], __ATOMIC_RELAXED, __HIP_MEMORY_SCOPE_AGENT);
    }
  }
  if (j < 64) hTout[b*256 + q*64 + j] = hst;
}

__global__ __launch_bounds__(256) void k_head(const float* __restrict__ hT,
    const float* __restrict__ Wc, const float* __restrict__ bc,
    float* __restrict__ out)
{
  int b = blockIdx.x, j = threadIdx.x;
  __shared__ float hs[256];
  hs[j] = hT[b*256 + j];
  __syncthreads();
  if (j < NC){
    float a = bc[j];
    for (int k=0; k<256; ++k) a += hs[k]*Wc[k*NC + j];
    out[b*NC + j] = a;
  }
}

// ---------------------------------------------------------------------------
extern "C" void kernel_launch(void* const* d_in, const int* in_sizes, int n_in,
                              void* d_out, int out_size, void* d_ws, size_t ws_size,
                              hipStream_t stream)
{
  if (ws_size < WS_TOTAL) return;

  const float* x    = (const float*)d_in[0];
  const float* eW1  = (const float*)d_in[1];
  const float* eg1  = (const float*)d_in[2];
  const float* eb1  = (const float*)d_in[3];
  const float* eW2  = (const float*)d_in[4];
  const float* eg2  = (const float*)d_in[5];
  const float* eb2  = (const float*)d_in[6];
  const float* eW3  = (const float*)d_in[7];
  const float* eg3  = (const float*)d_in[8];
  const float* eb3  = (const float*)d_in[9];
  const float* sW1  = (const float*)d_in[10];
  const float* sg1  = (const float*)d_in[11];
  const float* sb1  = (const float*)d_in[12];
  const float* sW2  = (const float*)d_in[13];
  const float* sg2  = (const float*)d_in[14];
  const float* sb2  = (const float*)d_in[15];
  const float* sW3  = (const float*)d_in[16];
  const float* sg3  = (const float*)d_in[17];
  const float* sb3  = (const float*)d_in[18];
  const float* rW   = (const float*)d_in[19];
  const float* rg   = (const float*)d_in[20];
  const float* rb   = (const float*)d_in[21];
  const float* rm1W = (const float*)d_in[22];
  const float* rm1b = (const float*)d_in[23];
  const float* rlng = (const float*)d_in[24];
  const float* rlnb = (const float*)d_in[25];
  const float* rm2W = (const float*)d_in[26];
  const float* rm2b = (const float*)d_in[27];
  const float* gW   = (const float*)d_in[28];
  const float* gb   = (const float*)d_in[29];
  const float* Wih  = (const float*)d_in[30];
  const float* Whh  = (const float*)d_in[31];
  const float* blst = (const float*)d_in[32];
  const float* Wc   = (const float*)d_in[33];
  const float* bc   = (const float*)d_in[34];

  char* ws = (char*)d_ws;
  f16*  ws1   = (f16*)(ws + OFF_WS1);
  f16*  ws2   = (f16*)(ws + OFF_WS2);
  f16*  ws3   = (f16*)(ws + OFF_WS3);
  f16*  we1   = (f16*)(ws + OFF_WE1);
  f16*  we2   = (f16*)(ws + OFF_WE2);
  f16*  we3   = (f16*)(ws + OFF_WE3);
  f16*  wr    = (f16*)(ws + OFF_WR);
  f16*  wih   = (f16*)(ws + OFF_WIH);
  u32*  whh   = (u32*)(ws + OFF_WHH);
  f16*  act0  = (f16*)(ws + OFF_ACT0);
  f16*  ract  = (f16*)(ws + OFF_RACT);
  f16*  amix  = (f16*)(ws + OFF_AMIX);
  f16*  convb = (f16*)(ws + OFF_CONV);
  f16*  a1    = (f16*)(ws + OFF_A1);
  f16*  a2    = (f16*)(ws + OFF_A2);
  f16*  Ubuf  = (f16*)(ws + OFF_U);
  float* stats = (float*)(ws + OFF_STAT);
  float* statsR= (float*)(ws + OFF_STATR);
  float* rh    = (float*)(ws + OFF_RH);
  int*   eidx  = (int*)(ws + OFF_EIDX);
  float* swt   = (float*)(ws + OFF_SWT);
  float* hTb   = (float*)(ws + OFF_HT);
  u32*   hxs   = (u32*)(ws + OFF_HX);
  u32*   flg   = (u32*)(ws + OFF_FLG);

  // ---- prep ----
  k_prep_w<<<(2349056 + 255)/256, 256, 0, stream>>>(eW1,eW2,eW3,sW1,sW2,sW3,rW,Wih,Whh,ws);
  k_prep_x<<<(B*T*32 + 255)/256, 256, 0, stream>>>(x, ws);

  // ---- router ----
  k_conv<32,5><<<dim3(8,2,64), 256, 0, stream>>>(act0, 0L, wr, nullptr, 0L, nullptr, convb, nullptr, 128);
  k_gnstats<16><<<64*8, 256, 0, stream>>>(convb, statsR);
  k_gnapply<16><<<2048, 256, 0, stream>>>(convb, statsR, rg, rb, nullptr, nullptr, nullptr, ract, 64*T*128/8);
  k_gap<<<B, 512, 0, stream>>>(ract, rh);
  k_router<<<B, 128, 0, stream>>>(rh, rm1W, rm1b, rlng, rlnb, rm2W, rm2b, gW, gb, eidx, swt);

  // ---- layer 1 (192 slot-units) ----
  k_conv<32,5><<<dim3(8,1,NU), 256, 0, stream>>>(act0, 0L, ws1, we1, (long)(5*64*32), eidx, convb, nullptr, 64);
  k_gnstats<8><<<NU*8, 256, 0, stream>>>(convb, stats);
  k_gnapply<8><<<3072, 256, 0, stream>>>(convb, stats, sg1, sb1, eg1, eb1, eidx, a1, NU*T*64/8);

  // ---- layer 2 ----
  k_conv<64,5><<<dim3(8,2,NU), 256, 0, stream>>>(a1, (long)T*64, ws2, we2, (long)(5*128*64), eidx, convb, nullptr, 128);
  k_gnstats<16><<<NU*8, 256, 0, stream>>>(convb, stats);
  k_gnapply<16><<<6144, 256, 0, stream>>>(convb, stats, sg2, sb2, eg2, eb2, eidx, a2, NU*T*128/8);

  // ---- layer 3 + weighted mix -> amix ----
  k_conv<128,5><<<dim3(8,4,NU), 256, 0, stream>>>(a2, (long)T*128, ws3, we3, (long)(5*256*128), eidx, convb, nullptr, 256);
  k_gnstats<32><<<NU*8, 256, 0, stream>>>(convb, stats);
  k_gnmix<<<4096, 256, 0, stream>>>(convb, stats, sg3, sb3, eg3, eb3, eidx, swt, amix);

  // ---- LSTM ----
  k_conv<256,1><<<dim3(8,16,64), 256, 0, stream>>>(amix, 0L, wih, nullptr, 0L, nullptr, Ubuf, blst, 1024);
  k_reset<<<4, 64, 0, stream>>>(flg);
  k_lstm<<<256, 256, 0, stream>>>(whh, Ubuf, hxs, flg, hTb);
  k_head<<<B, 256, 0, stream>>>(hTb, Wc, bc, (float*)d_out);
}

// Round 10
// 1656.502 us; speedup vs baseline: 3.9353x; 3.9353x over previous
//
#include <hip/hip_runtime.h>
#include <cstdint>
#include <cstddef>

// ---------------------------------------------------------------------------
// DeepCNNLSTM_EncoderMOE on MI355X (gfx950)
// Round 10: recombination of verified optima. LSTM = R5's exact kernel
// (867 us, single-WG-per-batch, L2-spill-tolerant). Pipeline = R6's
// compacted slot-unit launches (804 us). No new mechanisms.
// ---------------------------------------------------------------------------

#define DEVI __device__ __forceinline__

typedef _Float16 f16;
typedef _Float16 f16x8 __attribute__((ext_vector_type(8)));
typedef _Float16 f16x2 __attribute__((ext_vector_type(2)));
typedef float    f32x4 __attribute__((ext_vector_type(4)));
typedef unsigned int u32;
typedef unsigned short u16;

static constexpr int B   = 64;
static constexpr int T   = 512;
static constexpr int NC  = 10;
static constexpr int NU  = 192;   // slot-units: s=0,1 experts; s=2 shared

// ---- workspace layout (bytes) ----
constexpr size_t SZ_WS1 = (size_t)5*64*32*2;
constexpr size_t SZ_WS2 = (size_t)5*128*64*2;
constexpr size_t SZ_WS3 = (size_t)5*256*128*2;
constexpr size_t SZ_WE1 = 8*SZ_WS1;
constexpr size_t SZ_WE2 = 8*SZ_WS2;
constexpr size_t SZ_WE3 = 8*SZ_WS3;
constexpr size_t SZ_WR  = (size_t)5*128*32*2;
constexpr size_t SZ_WIH = (size_t)1024*256*2;
constexpr size_t SZ_WHH = (size_t)128*1024*4;
constexpr size_t SZ_ACT0 = (size_t)B*T*32*2;
constexpr size_t SZ_RACT = (size_t)B*T*128*2;
constexpr size_t SZ_AMIX = (size_t)B*T*256*2;
constexpr size_t SZ_CONV = (size_t)NU*T*256*2;
constexpr size_t SZ_A1   = (size_t)NU*T*64*2;
constexpr size_t SZ_A2   = (size_t)NU*T*128*2;
constexpr size_t SZ_U    = (size_t)B*T*1024*2;     // aliases CONV+A1+A2
constexpr size_t SZ_STAT = (size_t)NU*8*2*4;
constexpr size_t SZ_STATR= (size_t)B*8*2*4;
constexpr size_t SZ_RH   = (size_t)B*128*4;
constexpr size_t SZ_EIDX = (size_t)B*2*4;
constexpr size_t SZ_SWT  = (size_t)B*2*4;
constexpr size_t SZ_HT   = (size_t)B*256*4;

constexpr size_t OFF_WS1  = 0;
constexpr size_t OFF_WS2  = OFF_WS1 + SZ_WS1;
constexpr size_t OFF_WS3  = OFF_WS2 + SZ_WS2;
constexpr size_t OFF_WE1  = OFF_WS3 + SZ_WS3;
constexpr size_t OFF_WE2  = OFF_WE1 + SZ_WE1;
constexpr size_t OFF_WE3  = OFF_WE2 + SZ_WE2;
constexpr size_t OFF_WR   = OFF_WE3 + SZ_WE3;
constexpr size_t OFF_WIH  = OFF_WR  + SZ_WR;
constexpr size_t OFF_WHH  = OFF_WIH + SZ_WIH;
constexpr size_t OFF_ACT0 = OFF_WHH + SZ_WHH;
constexpr size_t OFF_RACT = OFF_ACT0 + SZ_ACT0;
constexpr size_t OFF_AMIX = OFF_RACT + SZ_RACT;
constexpr size_t OFF_CONV = OFF_AMIX + SZ_AMIX;
constexpr size_t OFF_A1   = OFF_CONV + SZ_CONV;
constexpr size_t OFF_A2   = OFF_A1 + SZ_A1;
constexpr size_t OFF_U    = OFF_CONV;              // alias
constexpr size_t OFF_STAT = OFF_A2 + SZ_A2;
constexpr size_t OFF_STATR= OFF_STAT + SZ_STAT;
constexpr size_t OFF_RH   = OFF_STATR + SZ_STATR;
constexpr size_t OFF_EIDX = OFF_RH + SZ_RH;
constexpr size_t OFF_SWT  = OFF_EIDX + SZ_EIDX;
constexpr size_t OFF_HT   = OFF_SWT + SZ_SWT;
constexpr size_t WS_TOTAL = OFF_HT + SZ_HT;

static_assert(SZ_U <= SZ_CONV + SZ_A1 + SZ_A2, "U alias overflow");

DEVI float geluf(float x){ return 0.5f*x*(1.f + erff(x*0.70710678118654752f)); }
DEVI float fsig(float x){ return 1.f/(1.f + __expf(-x)); }
DEVI float ftanh(float x){ float e = __expf(-2.f*x); return (1.f-e)/(1.f+e); }

// ---------------------------------------------------------------------------
// Weight prep
// ---------------------------------------------------------------------------
DEVI void fill_convw(f16* dst, const float* src, int COUT, int CI, int CIP, int idx){
  int s  = idx / (COUT*CIP);
  int r  = idx - s*(COUT*CIP);
  int co = r / CIP;
  int ci = r - co*CIP;
  float v = (ci < CI) ? src[((size_t)co*CI + ci)*5 + s] : 0.f;
  dst[idx] = (f16)v;
}

__global__ __launch_bounds__(256) void k_prep_w(
    const float* eW1, const float* eW2, const float* eW3,
    const float* sW1, const float* sW2, const float* sW3, const float* rW,
    const float* Wih, const float* Whh, char* ws)
{
  int i = blockIdx.x*256 + threadIdx.x;
  if (i < 10240){ fill_convw((f16*)(ws+OFF_WS1), sW1, 64, 16, 32, i); return; } i -= 10240;
  if (i < 40960){ fill_convw((f16*)(ws+OFF_WS2), sW2, 128, 64, 64, i); return; } i -= 40960;
  if (i < 163840){ fill_convw((f16*)(ws+OFF_WS3), sW3, 256, 128, 128, i); return; } i -= 163840;
  if (i < 81920){ int e=i/10240, r=i-e*10240;
    fill_convw((f16*)(ws+OFF_WE1)+ (size_t)e*10240, eW1 + (size_t)e*64*16*5, 64, 16, 32, r); return; } i -= 81920;
  if (i < 327680){ int e=i/40960, r=i-e*40960;
    fill_convw((f16*)(ws+OFF_WE2)+ (size_t)e*40960, eW2 + (size_t)e*128*64*5, 128, 64, 64, r); return; } i -= 327680;
  if (i < 1310720){ int e=i/163840, r=i-e*163840;
    fill_convw((f16*)(ws+OFF_WE3)+ (size_t)e*163840, eW3 + (size_t)e*163840, 256, 128, 128, r); return; } i -= 1310720;
  if (i < 20480){ fill_convw((f16*)(ws+OFF_WR), rW, 128, 16, 32, i); return; } i -= 20480;
  if (i < 262144){ // W_ih (256,1024) -> [j][k]
    int j = i >> 8, k = i & 255;
    ((f16*)(ws+OFF_WIH))[i] = (f16)Wih[(size_t)k*1024 + j]; return; } i -= 262144;
  if (i < 131072){ // W_hh -> packed row-pairs [pair][1024]
    int i2 = i >> 10, j = i & 1023;
    f16 a = (f16)Whh[(size_t)(2*i2)*1024 + j];
    f16 b = (f16)Whh[(size_t)(2*i2+1)*1024 + j];
    u32 u = (u32)__builtin_bit_cast(unsigned short, a)
          | ((u32)__builtin_bit_cast(unsigned short, b) << 16);
    ((u32*)(ws+OFF_WHH))[i] = u; return; }
}

__global__ __launch_bounds__(256) void k_prep_x(const float* __restrict__ x, char* ws){
  int idx = blockIdx.x*256 + threadIdx.x;
  if (idx >= B*T*32) return;
  int b = idx/(T*32); int r = idx - b*(T*32); int t = r >> 5; int c = r & 31;
  f16 v = (c < 16) ? (f16)x[((size_t)b*16 + c)*T + t] : (f16)0.f;
  ((f16*)(ws+OFF_ACT0))[idx] = v;
}

// ---------------------------------------------------------------------------
// Conv / GEMM via MFMA f16, slot-unit grid (blockIdx.z = unit).
// ---------------------------------------------------------------------------
template<int CIN, int NSHIFT>
__global__ __launch_bounds__(256) void k_conv(
    const f16* __restrict__ act, long actUnitStride,
    const f16* __restrict__ wtS, const f16* __restrict__ wtE, long wtEStride,
    const int* __restrict__ eidx,
    f16* __restrict__ outp, const float* __restrict__ bias, int COUT)
{
  int u = blockIdx.z;
  int s = u >> 6, b = u & 63;
  const f16* wt = wtS;
  if (eidx && s < 2) wt = wtE + (size_t)eidx[b*2+s]*wtEStride;
  const f16* abase = act + (actUnitStride ? (size_t)u*actUnitStride
                                          : (size_t)b*T*CIN);
  f16* obase = outp + (size_t)u*T*COUT;

  int t0 = blockIdx.x << 6;
  int n0 = blockIdx.y << 6;
  int tid  = threadIdx.x;
  int wave = tid >> 6, lane = tid & 63;
  int lr = lane & 15, lk = lane >> 4;

  f32x4 acc[4];
  #pragma unroll
  for (int nf=0; nf<4; ++nf) acc[nf] = f32x4{0.f,0.f,0.f,0.f};

  int trow = t0 + wave*16 + lr;

  #pragma unroll
  for (int sh=0; sh<NSHIFT; ++sh){
    int tg = (NSHIFT==5) ? (trow + sh - 2) : trow;
    bool valid = (unsigned)tg < (unsigned)T;
    const f16* arow = abase + (long)tg*CIN + lk*8;
    #pragma unroll
    for (int c0=0; c0<CIN; c0+=32){
      f16x8 af = {(f16)0,(f16)0,(f16)0,(f16)0,(f16)0,(f16)0,(f16)0,(f16)0};
      if (valid) af = *(const f16x8*)(arow + c0);
      #pragma unroll
      for (int nf=0; nf<4; ++nf){
        int col = n0 + nf*16 + lr;
        f16x8 bf = *(const f16x8*)(wt + ((size_t)sh*COUT + col)*CIN + c0 + lk*8);
        acc[nf] = __builtin_amdgcn_mfma_f32_16x16x32_f16(af, bf, acc[nf], 0, 0, 0);
      }
    }
  }

  #pragma unroll
  for (int nf=0; nf<4; ++nf){
    int col = n0 + nf*16 + lr;
    float bv = bias ? bias[col] : 0.f;
    #pragma unroll
    for (int r=0; r<4; ++r){
      int trw = t0 + wave*16 + lk*4 + r;
      obase[(size_t)trw*COUT + col] = (f16)(acc[nf][r] + bv);
    }
  }
}

// ---------------------------------------------------------------------------
// GroupNorm stats per (unit, g)
// ---------------------------------------------------------------------------
template<int CPG>
__global__ __launch_bounds__(256) void k_gnstats(
    const f16* __restrict__ xin, float* __restrict__ stats)
{
  constexpr int C = CPG*8;
  constexpr int V = CPG/8;
  int u = blockIdx.x >> 3, g = blockIdx.x & 7;
  const f16* base = xin + (size_t)u*T*C + g*CPG;
  float sum = 0.f, ss = 0.f;
  for (int i = threadIdx.x; i < T*V; i += 256){
    int t = i / V, v = i - (i/V)*V;
    f16x8 xv = *(const f16x8*)(base + (size_t)t*C + v*8);
    #pragma unroll
    for (int k=0;k<8;++k){ float f = (float)xv[k]; sum += f; ss += f*f; }
  }
  #pragma unroll
  for (int off=32; off; off>>=1){ sum += __shfl_down(sum, off); ss += __shfl_down(ss, off); }
  __shared__ float rs[8];
  int wave = threadIdx.x >> 6, lane = threadIdx.x & 63;
  if (lane == 0){ rs[wave] = sum; rs[4+wave] = ss; }
  __syncthreads();
  if (threadIdx.x == 0){
    float S = rs[0]+rs[1]+rs[2]+rs[3], Q = rs[4]+rs[5]+rs[6]+rs[7];
    constexpr float N = (float)(CPG*T);
    float m = S/N;
    float var = Q/N - m*m;
    stats[(u*8+g)*2]   = m;
    stats[(u*8+g)*2+1] = rsqrtf(var + 1e-5f);
  }
}

// ---------------------------------------------------------------------------
// GN apply + GELU -> f16 act (slot region)
// ---------------------------------------------------------------------------
template<int CPG>
__global__ __launch_bounds__(256) void k_gnapply(
    const f16* __restrict__ xin, const float* __restrict__ stats,
    const float* __restrict__ gS, const float* __restrict__ bS,
    const float* __restrict__ gE, const float* __restrict__ bE,
    const int* __restrict__ eidx, f16* __restrict__ outp, int total8)
{
  constexpr int C = CPG*8;
  int idx = blockIdx.x*256 + threadIdx.x;
  if (idx >= total8) return;
  size_t base = (size_t)idx*8;
  int u = (int)(base / ((size_t)T*C));
  int s = u >> 6, b = u & 63;
  const float* gamma = gS; const float* beta = bS;
  if (eidx && s < 2){ int e = eidx[b*2+s]; gamma = gE + e*C; beta = bE + e*C; }
  int c0 = (int)(base % C);
  int g  = c0 / CPG;
  float m  = stats[(u*8+g)*2];
  float rstd = stats[(u*8+g)*2+1];
  f16x8 xv = *(const f16x8*)(xin + base);
  f16x8 h8;
  #pragma unroll
  for (int k=0; k<8; ++k){
    float xn = ((float)xv[k]-m)*rstd*gamma[c0+k] + beta[c0+k];
    h8[k] = (f16)geluf(xn);
  }
  *(f16x8*)(outp + base) = h8;
}

// ---------------------------------------------------------------------------
// L3 GN + GELU + weighted slot-mix -> amix f16
// ---------------------------------------------------------------------------
__global__ __launch_bounds__(256) void k_gnmix(
    const f16* __restrict__ conv, const float* __restrict__ stats,
    const float* __restrict__ sg, const float* __restrict__ sb,
    const float* __restrict__ eg, const float* __restrict__ eb,
    const int* __restrict__ eidx, const float* __restrict__ swt,
    f16* __restrict__ amix)
{
  size_t base = ((size_t)blockIdx.x*256 + threadIdx.x)*8;
  if (base >= (size_t)B*T*256) return;
  int b = (int)(base / ((size_t)T*256));
  size_t rem = base - (size_t)b*T*256;
  int c0 = (int)(rem & 255);
  int g  = c0 >> 5;
  float o[8] = {0.f,0.f,0.f,0.f,0.f,0.f,0.f,0.f};
  #pragma unroll
  for (int s=0; s<3; ++s){
    int u = s*64 + b;
    float w; const float *gamma, *beta;
    if (s < 2){ int e = eidx[b*2+s]; w = swt[b*2+s]; gamma = eg + e*256; beta = eb + e*256; }
    else      { w = 1.f; gamma = sg; beta = sb; }
    float m = stats[(u*8+g)*2], rstd = stats[(u*8+g)*2+1];
    f16x8 xv = *(const f16x8*)(conv + (size_t)u*T*256 + rem);
    #pragma unroll
    for (int k=0; k<8; ++k){
      float xn = ((float)xv[k]-m)*rstd*gamma[c0+k] + beta[c0+k];
      o[k] += w*geluf(xn);
    }
  }
  f16x8 h8;
  #pragma unroll
  for (int k=0; k<8; ++k) h8[k] = (f16)o[k];
  *(f16x8*)(amix + base) = h8;
}

// ---------------------------------------------------------------------------
// Router
// ---------------------------------------------------------------------------
__global__ __launch_bounds__(512) void k_gap(const f16* __restrict__ ract,
                                             float* __restrict__ rh){
  int b = blockIdx.x;
  int c = threadIdx.x & 127, st = threadIdx.x >> 7;
  const f16* p = ract + (size_t)b*T*128 + c;
  float s = 0.f;
  for (int t = st; t < T; t += 4) s += (float)p[(size_t)t*128];
  __shared__ float acc[512];
  acc[threadIdx.x] = s;
  __syncthreads();
  if (st == 0) rh[b*128 + c] = (acc[c] + acc[128+c] + acc[256+c] + acc[384+c]) * (1.f/(float)T);
}

__global__ __launch_bounds__(128) void k_router(
    const float* __restrict__ rh,
    const float* __restrict__ m1W, const float* __restrict__ m1b,
    const float* __restrict__ lng, const float* __restrict__ lnb,
    const float* __restrict__ m2W, const float* __restrict__ m2b,
    const float* __restrict__ gW,  const float* __restrict__ gb,
    int* __restrict__ eidx, float* __restrict__ swt)
{
  int b = blockIdx.x, j = threadIdx.x;
  __shared__ float sbuf[128];
  __shared__ float red[4];
  __shared__ float z2[64];
  sbuf[j] = rh[b*128 + j];
  __syncthreads();
  float acc = m1b[j];
  for (int k=0; k<128; ++k) acc += sbuf[k]*m1W[k*128 + j];
  float s1 = acc, s2 = acc*acc;
  #pragma unroll
  for (int off=32; off; off>>=1){ s1 += __shfl_down(s1, off); s2 += __shfl_down(s2, off); }
  int wid = j >> 6, lane = j & 63;
  if (lane == 0){ red[wid] = s1; red[2+wid] = s2; }
  __syncthreads();
  float S = red[0]+red[1], Q = red[2]+red[3];
  float m = S*(1.f/128.f), var = Q*(1.f/128.f) - m*m;
  float xn = (acc - m)*rsqrtf(var + 1e-5f)*lng[j] + lnb[j];
  float ge = geluf(xn);
  __syncthreads();
  sbuf[j] = ge;
  __syncthreads();
  if (j < 64){
    float a = m2b[j];
    for (int k=0; k<128; ++k) a += sbuf[k]*m2W[k*64 + j];
    z2[j] = a;
  }
  __syncthreads();
  if (j == 0){
    float lg[8];
    for (int e=0; e<8; ++e){
      float a = gb[e];
      for (int k=0; k<64; ++k) a += z2[k]*gW[k*8 + e];
      lg[e] = a;
    }
    float mx = lg[0];
    for (int e=1; e<8; ++e) mx = fmaxf(mx, lg[e]);
    float p[8], sum = 0.f;
    for (int e=0; e<8; ++e){ p[e] = __expf(lg[e]-mx); sum += p[e]; }
    float inv = 1.f/sum;
    for (int e=0; e<8; ++e) p[e] *= inv;
    int i1 = 0;
    for (int e=1; e<8; ++e) if (p[e] > p[i1]) i1 = e;
    int i2 = -1;
    for (int e=0; e<8; ++e){ if (e==i1) continue; if (i2 < 0 || p[e] > p[i2]) i2 = e; }
    float s = p[i1] + p[i2] + 1e-9f;
    eidx[b*2]   = i1;  swt[b*2]   = p[i1]/s;
    eidx[b*2+1] = i2;  swt[b*2+1] = p[i2]/s;
  }
}

// ---------------------------------------------------------------------------
// Persistent LSTM (R5-verified, 867us): 64 WGs x 512 threads (8 waves).
// Thread (half = j>>8, d = j&255) owns cols {half*256+d, 512+half*256+d}:
// half0 -> (i,g) of dim d, half1 -> (f,o) of dim d.
// Pairs [0,100) per col in VGPRs; pairs [100,128) in LDS [pair][1024] u32.
// h double-buffered (128 packed u32); f,o exchanged via gbuf; 2 barriers/step.
// ---------------------------------------------------------------------------
constexpr int PV5 = 100;     // pairs per column in VGPRs
constexpr int PLQ = 7;       // LDS pair-quads (28 pairs)

DEVI float dot2acc(u32 wu, u32 hu, float acc){
#if __has_builtin(__builtin_amdgcn_fdot2)
  return __builtin_amdgcn_fdot2(__builtin_bit_cast(f16x2, wu),
                                __builtin_bit_cast(f16x2, hu), acc, false);
#else
  f16x2 a = __builtin_bit_cast(f16x2, wu), b = __builtin_bit_cast(f16x2, hu);
  return acc + (float)a.x*(float)b.x + (float)a.y*(float)b.y;
#endif
}

__global__ __attribute__((amdgpu_flat_work_group_size(512,512), amdgpu_waves_per_eu(2,2)))
void k_lstm(const u32* __restrict__ whh, const f16* __restrict__ U,
            float* __restrict__ hTout)
{
  int b = blockIdx.x, j = threadIdx.x;
  int d = j & 255, half = j >> 8;
  int colA = half*256 + d;        // i (half0) or f (half1)
  int colB = 512 + colA;          // g (half0) or o (half1)

  __shared__ u32 wl[PLQ*4*1024];              // 112 KB: pairs [100,128)
  __shared__ __align__(16) u32 hbuf[2][128];  // packed f16 h, double-buffered
  __shared__ float gbF[256], gbO[256];

  u32 wA[PV5], wB[PV5];
  #pragma unroll
  for (int i=0; i<PV5; ++i){
    wA[i] = whh[(size_t)i*1024 + colA];
    wB[i] = whh[(size_t)i*1024 + colB];
  }
  for (int idx = j; idx < PLQ*4*1024; idx += 512){
    int p = idx >> 10, c = idx & 1023;
    wl[idx] = whh[(size_t)(PV5+p)*1024 + c];
  }
  if (j < 128) hbuf[0][j] = 0u;

  float cst = 0.f, hst = 0.f;
  const f16* Ub = U + (size_t)b*T*1024;
  float uA = (float)Ub[colA], uB = (float)Ub[colB];
  __syncthreads();

  int cur = 0;
  for (int t=0; t<T; ++t){
    float aA = uA, aB = uB;
    if (t+1 < T){
      const f16* un = Ub + (size_t)(t+1)*1024;
      uA = (float)un[colA]; uB = (float)un[colB];
    }
    const uint4* hp4 = (const uint4*)hbuf[cur];
    #pragma unroll
    for (int q=0; q<PV5/4; ++q){
      uint4 hq = hp4[q];
      aA = dot2acc(wA[4*q+0], hq.x, aA); aB = dot2acc(wB[4*q+0], hq.x, aB);
      aA = dot2acc(wA[4*q+1], hq.y, aA); aB = dot2acc(wB[4*q+1], hq.y, aB);
      aA = dot2acc(wA[4*q+2], hq.z, aA); aB = dot2acc(wB[4*q+2], hq.z, aB);
      aA = dot2acc(wA[4*q+3], hq.w, aA); aB = dot2acc(wB[4*q+3], hq.w, aB);
    }
    #pragma unroll
    for (int k=0; k<PLQ; ++k){
      uint4 hq = hp4[PV5/4 + k];
      u32 a0 = wl[(4*k+0)*1024 + colA], b0 = wl[(4*k+0)*1024 + colB];
      u32 a1 = wl[(4*k+1)*1024 + colA], b1 = wl[(4*k+1)*1024 + colB];
      u32 a2 = wl[(4*k+2)*1024 + colA], b2 = wl[(4*k+2)*1024 + colB];
      u32 a3 = wl[(4*k+3)*1024 + colA], b3 = wl[(4*k+3)*1024 + colB];
      aA = dot2acc(a0, hq.x, aA); aB = dot2acc(b0, hq.x, aB);
      aA = dot2acc(a1, hq.y, aA); aB = dot2acc(b1, hq.y, aB);
      aA = dot2acc(a2, hq.z, aA); aB = dot2acc(b2, hq.z, aB);
      aA = dot2acc(a3, hq.w, aA); aB = dot2acc(b3, hq.w, aB);
    }
    if (half){ gbF[d] = aA; gbO[d] = aB; }
    __syncthreads();
    if (!half){
      float gi = aA, gg = aB, gf = gbF[d], go = gbO[d];
      cst = fsig(gf)*cst + fsig(gi)*ftanh(gg);
      hst = fsig(go)*ftanh(cst);
      u16* hn = (u16*)hbuf[cur^1];
      hn[d] = __builtin_bit_cast(u16, (f16)hst);
    }
    __syncthreads();
    cur ^= 1;
  }
  if (!half) hTout[b*256 + d] = hst;
}

__global__ __launch_bounds__(256) void k_head(const float* __restrict__ hT,
    const float* __restrict__ Wc, const float* __restrict__ bc,
    float* __restrict__ out)
{
  int b = blockIdx.x, j = threadIdx.x;
  __shared__ float hs[256];
  hs[j] = hT[b*256 + j];
  __syncthreads();
  if (j < NC){
    float a = bc[j];
    for (int k=0; k<256; ++k) a += hs[k]*Wc[k*NC + j];
    out[b*NC + j] = a;
  }
}

// ---------------------------------------------------------------------------
extern "C" void kernel_launch(void* const* d_in, const int* in_sizes, int n_in,
                              void* d_out, int out_size, void* d_ws, size_t ws_size,
                              hipStream_t stream)
{
  if (ws_size < WS_TOTAL) return;

  const float* x    = (const float*)d_in[0];
  const float* eW1  = (const float*)d_in[1];
  const float* eg1  = (const float*)d_in[2];
  const float* eb1  = (const float*)d_in[3];
  const float* eW2  = (const float*)d_in[4];
  const float* eg2  = (const float*)d_in[5];
  const float* eb2  = (const float*)d_in[6];
  const float* eW3  = (const float*)d_in[7];
  const float* eg3  = (const float*)d_in[8];
  const float* eb3  = (const float*)d_in[9];
  const float* sW1  = (const float*)d_in[10];
  const float* sg1  = (const float*)d_in[11];
  const float* sb1  = (const float*)d_in[12];
  const float* sW2  = (const float*)d_in[13];
  const float* sg2  = (const float*)d_in[14];
  const float* sb2  = (const float*)d_in[15];
  const float* sW3  = (const float*)d_in[16];
  const float* sg3  = (const float*)d_in[17];
  const float* sb3  = (const float*)d_in[18];
  const float* rW   = (const float*)d_in[19];
  const float* rg   = (const float*)d_in[20];
  const float* rb   = (const float*)d_in[21];
  const float* rm1W = (const float*)d_in[22];
  const float* rm1b = (const float*)d_in[23];
  const float* rlng = (const float*)d_in[24];
  const float* rlnb = (const float*)d_in[25];
  const float* rm2W = (const float*)d_in[26];
  const float* rm2b = (const float*)d_in[27];
  const float* gW   = (const float*)d_in[28];
  const float* gb   = (const float*)d_in[29];
  const float* Wih  = (const float*)d_in[30];
  const float* Whh  = (const float*)d_in[31];
  const float* blst = (const float*)d_in[32];
  const float* Wc   = (const float*)d_in[33];
  const float* bc   = (const float*)d_in[34];

  char* ws = (char*)d_ws;
  f16*  ws1   = (f16*)(ws + OFF_WS1);
  f16*  ws2   = (f16*)(ws + OFF_WS2);
  f16*  ws3   = (f16*)(ws + OFF_WS3);
  f16*  we1   = (f16*)(ws + OFF_WE1);
  f16*  we2   = (f16*)(ws + OFF_WE2);
  f16*  we3   = (f16*)(ws + OFF_WE3);
  f16*  wr    = (f16*)(ws + OFF_WR);
  f16*  wih   = (f16*)(ws + OFF_WIH);
  u32*  whh   = (u32*)(ws + OFF_WHH);
  f16*  act0  = (f16*)(ws + OFF_ACT0);
  f16*  ract  = (f16*)(ws + OFF_RACT);
  f16*  amix  = (f16*)(ws + OFF_AMIX);
  f16*  convb = (f16*)(ws + OFF_CONV);
  f16*  a1    = (f16*)(ws + OFF_A1);
  f16*  a2    = (f16*)(ws + OFF_A2);
  f16*  Ubuf  = (f16*)(ws + OFF_U);
  float* stats = (float*)(ws + OFF_STAT);
  float* statsR= (float*)(ws + OFF_STATR);
  float* rh    = (float*)(ws + OFF_RH);
  int*   eidx  = (int*)(ws + OFF_EIDX);
  float* swt   = (float*)(ws + OFF_SWT);
  float* hTb   = (float*)(ws + OFF_HT);

  // ---- prep ----
  k_prep_w<<<(2349056 + 255)/256, 256, 0, stream>>>(eW1,eW2,eW3,sW1,sW2,sW3,rW,Wih,Whh,ws);
  k_prep_x<<<(B*T*32 + 255)/256, 256, 0, stream>>>(x, ws);

  // ---- router ----
  k_conv<32,5><<<dim3(8,2,64), 256, 0, stream>>>(act0, 0L, wr, nullptr, 0L, nullptr, convb, nullptr, 128);
  k_gnstats<16><<<64*8, 256, 0, stream>>>(convb, statsR);
  k_gnapply<16><<<2048, 256, 0, stream>>>(convb, statsR, rg, rb, nullptr, nullptr, nullptr, ract, 64*T*128/8);
  k_gap<<<B, 512, 0, stream>>>(ract, rh);
  k_router<<<B, 128, 0, stream>>>(rh, rm1W, rm1b, rlng, rlnb, rm2W, rm2b, gW, gb, eidx, swt);

  // ---- layer 1 (192 slot-units) ----
  k_conv<32,5><<<dim3(8,1,NU), 256, 0, stream>>>(act0, 0L, ws1, we1, (long)(5*64*32), eidx, convb, nullptr, 64);
  k_gnstats<8><<<NU*8, 256, 0, stream>>>(convb, stats);
  k_gnapply<8><<<3072, 256, 0, stream>>>(convb, stats, sg1, sb1, eg1, eb1, eidx, a1, NU*T*64/8);

  // ---- layer 2 ----
  k_conv<64,5><<<dim3(8,2,NU), 256, 0, stream>>>(a1, (long)T*64, ws2, we2, (long)(5*128*64), eidx, convb, nullptr, 128);
  k_gnstats<16><<<NU*8, 256, 0, stream>>>(convb, stats);
  k_gnapply<16><<<6144, 256, 0, stream>>>(convb, stats, sg2, sb2, eg2, eb2, eidx, a2, NU*T*128/8);

  // ---- layer 3 + weighted mix -> amix ----
  k_conv<128,5><<<dim3(8,4,NU), 256, 0, stream>>>(a2, (long)T*128, ws3, we3, (long)(5*256*128), eidx, convb, nullptr, 256);
  k_gnstats<32><<<NU*8, 256, 0, stream>>>(convb, stats);
  k_gnmix<<<4096, 256, 0, stream>>>(convb, stats, sg3, sb3, eg3, eb3, eidx, swt, amix);

  // ---- LSTM ----
  k_conv<256,1><<<dim3(8,16,64), 256, 0, stream>>>(amix, 0L, wih, nullptr, 0L, nullptr, Ubuf, blst, 1024);
  k_lstm<<<B, 512, 0, stream>>>(whh, Ubuf, hTb);
  k_head<<<B, 256, 0, stream>>>(hTb, Wc, bc, (float*)d_out);
}